// Round 6
// baseline (1632.816 us; speedup 1.0000x reference)
//
#include <hip/hip_runtime.h>

// RNNPolicy fused kernel for MI355X — round 5: LDS-pipe de-contention.
// 256 blocks (1 batch chain / CU), 256 threads = 4 waves, interval = 64 timesteps.
//
// Waves (interval n, batch m = 64 timesteps, all handoffs via swizzled LDS):
//   wave0 P0: stage x(m=n+1) global->LDS; a0-proj(m=n) lane=t, uniform-W s_loads;
//             head half j<32 (m=n-4) -> partial to Hd0.
//   wave1 R0: layer-0 recurrence (m=n-1): h in VGPRs, v_readlane broadcast dot
//             (NO LDS in the dot), tanh; writes h0 rows for P1.
//   wave2 P1: combine+store out (m=n-5); a1-proj(m=n-2) lane=t; head half j>=32
//             (m=n-4) -> partials held in regs.
//   wave3 R1: layer-1 recurrence (m=n-3), like R0; writes h1 rows for head.
// XOR-quad swizzle pq = lq^(t&7) on all 64x64 tiles: row accesses (b32)
// conflict-free, per-lane transpose accesses (b128) 8-way (~2.9x, cheap).

#define T_LEN 2048
#define BATCH 64
#define NITV  (T_LEN / BATCH)   // 32
#define NLOOP (NITV + 5)        // 37 intervals

// flat index into a [64][64] tile: row t, logical col c, quad-swizzled
__device__ __forceinline__ int swz(int t, int c) {
  return t * 64 + ((((c >> 2) ^ (t & 7)) << 2) | (c & 3));
}

__global__ __launch_bounds__(256, 1) void rnn_fused(
    const float* __restrict__ x,
    const float* __restrict__ Wih0, const float* __restrict__ Whh0,
    const float* __restrict__ bih0, const float* __restrict__ bhh0,
    const float* __restrict__ Wih1, const float* __restrict__ Whh1,
    const float* __restrict__ bih1, const float* __restrict__ bhh1,
    const float* __restrict__ W1, const float* __restrict__ b1,
    const float* __restrict__ W2, const float* __restrict__ b2,
    float* __restrict__ out) {
  __shared__ __align__(16) float Xc[2][4096];   // x chunks (swizzled)
  __shared__ __align__(16) float A0[2][4096];   // a0 pre-activations
  __shared__ __align__(16) float P3[3][4096];   // pool: h0[m] then a1[m], slot m%3
  __shared__ __align__(16) float H1[2][4096];   // h1 rows
  __shared__ __align__(8)  float Hd0[2][64][2]; // head partial (j<32)

  const int tid  = threadIdx.x;
  const int wave = tid >> 6;
  const int lane = tid & 63;
  const int b    = blockIdx.x;
  const size_t xbase = (size_t)b * T_LEN * 64;

  // Prologue: wave0 stages x batch m=0 into Xc[0].
  if (wave == 0) {
#pragma unroll
    for (int it = 0; it < 16; ++it) {
      const int fi = it * 64 + lane;          // float4 index 0..1023
      const int t  = fi >> 4, lq = fi & 15;
      float4 v = *(const float4*)(x + xbase + fi * 4);
      *(float4*)&Xc[0][swz(t, lq * 4)] = v;
    }
  }
  __syncthreads();

  if (wave == 1 || wave == 3) {
    // ---------------- recurrence waves ----------------
    const float* wsrc = (wave == 1) ? Whh0 : Whh1;
    float w[64];
#pragma unroll
    for (int q = 0; q < 16; ++q) {
      float4 v = *(const float4*)(wsrc + lane * 64 + 4 * q);
      w[4*q+0] = v.x; w[4*q+1] = v.y; w[4*q+2] = v.z; w[4*q+3] = v.w;
    }
    const int dly = (wave == 1) ? 1 : 3;
    float h = 0.f;                             // lane j holds h[t-1][j]
    for (int n = 0; n < NLOOP; ++n) {
      const int m = n - dly;
      if (m >= 0 && m < NITV) {
        const float* Ain = (wave == 1) ? &A0[m & 1][0] : &P3[m % 3][0];
        float* Hout      = (wave == 1) ? &P3[m % 3][0] : &H1[m & 1][0];
        for (int tt = 0; tt < 64; ++tt) {
          const int idx = swz(tt, lane);
          float av = Ain[idx];                 // ds_read issues; lands during dot
          const int hb = __float_as_int(h);
          float c0 = 0.f, c1 = 0.f, c2 = 0.f, c3 = 0.f;
#pragma unroll
          for (int k = 0; k < 64; k += 4) {
            c0 = fmaf(__int_as_float(__builtin_amdgcn_readlane(hb, k+0)), w[k+0], c0);
            c1 = fmaf(__int_as_float(__builtin_amdgcn_readlane(hb, k+1)), w[k+1], c1);
            c2 = fmaf(__int_as_float(__builtin_amdgcn_readlane(hb, k+2)), w[k+2], c2);
            c3 = fmaf(__int_as_float(__builtin_amdgcn_readlane(hb, k+3)), w[k+3], c3);
          }
          const float pre = av + ((c0 + c1) + (c2 + c3));
          const float e = __expf(2.f * pre);   // tanh = 1 - 2/(e^{2x}+1)
          h = fmaf(-2.f, __builtin_amdgcn_rcpf(e + 1.f), 1.f);
          Hout[idx] = h;
        }
      }
      __syncthreads();
    }
  } else if (wave == 0) {
    // ---------------- P0: stage + a0-proj + head(j<32) ----------------
    for (int n = 0; n < NLOOP; ++n) {
      // (1) issue global loads for x batch m=n+1
      float4 px[16];
      const bool st = (n + 1) < NITV;
      if (st) {
        const float* src = x + xbase + (size_t)(n + 1) * BATCH * 64;
#pragma unroll
        for (int it = 0; it < 16; ++it) px[it] = *(const float4*)(src + (it * 64 + lane) * 4);
      }
      // (2) a0-proj, m=n, lane = t
      if (n < NITV) {
        float xr[64];
#pragma unroll
        for (int lq = 0; lq < 16; ++lq) {
          float4 v = *(const float4*)&Xc[n & 1][swz(lane, lq * 4)];
          xr[4*lq+0] = v.x; xr[4*lq+1] = v.y; xr[4*lq+2] = v.z; xr[4*lq+3] = v.w;
        }
        float* Aout = &A0[n & 1][0];
        for (int g = 0; g < 8; ++g) {
          const int jb = g * 8;
          float acc[8];
#pragma unroll
          for (int jj = 0; jj < 8; ++jj) acc[jj] = bih0[jb+jj] + bhh0[jb+jj];
#pragma unroll
          for (int jj = 0; jj < 8; ++jj) {
            const float* wr = Wih0 + (jb + jj) * 64;
#pragma unroll
            for (int k = 0; k < 64; ++k) acc[jj] = fmaf(wr[k], xr[k], acc[jj]);
          }
          *(float4*)&Aout[swz(lane, jb)]     = make_float4(acc[0], acc[1], acc[2], acc[3]);
          *(float4*)&Aout[swz(lane, jb + 4)] = make_float4(acc[4], acc[5], acc[6], acc[7]);
        }
      }
      // (3) head half j<32, m = n-4
      if (n >= 4 && n - 4 < NITV) {
        const int m = n - 4;
        float hr[64];
#pragma unroll
        for (int lq = 0; lq < 16; ++lq) {
          float4 v = *(const float4*)&H1[m & 1][swz(lane, lq * 4)];
          hr[4*lq+0] = v.x; hr[4*lq+1] = v.y; hr[4*lq+2] = v.z; hr[4*lq+3] = v.w;
        }
        float p0 = 0.f, p1 = 0.f;
        for (int j = 0; j < 32; ++j) {
          float za = b1[j], zb = 0.f, zc = 0.f, zd = 0.f;
          const float* wr = W1 + j * 64;
#pragma unroll
          for (int k = 0; k < 64; k += 4) {
            za = fmaf(wr[k+0], hr[k+0], za); zb = fmaf(wr[k+1], hr[k+1], zb);
            zc = fmaf(wr[k+2], hr[k+2], zc); zd = fmaf(wr[k+3], hr[k+3], zd);
          }
          const float zv = fmaxf((za + zb) + (zc + zd), 0.f);
          p0 = fmaf(W2[j], zv, p0);
          p1 = fmaf(W2[64 + j], zv, p1);
        }
        *(float2*)&Hd0[m & 1][lane][0] = make_float2(p0, p1);
      }
      // (4) write staged x
      if (st) {
#pragma unroll
        for (int it = 0; it < 16; ++it) {
          const int fi = it * 64 + lane;
          const int t = fi >> 4, lq = fi & 15;
          *(float4*)&Xc[(n + 1) & 1][swz(t, lq * 4)] = px[it];
        }
      }
      __syncthreads();
    }
  } else {
    // ---------------- P1 (wave2): store + a1-proj + head(j>=32) ----------------
    float hp0 = 0.f, hp1 = 0.f;   // held head partials (m = n-5 at use time)
    for (int n = 0; n < NLOOP; ++n) {
      // (1) combine + store out, m = n-5
      if (n >= 5 && n - 5 < NITV) {
        const int m = n - 5;
        const float2 q = *(const float2*)&Hd0[m & 1][lane][0];
        float2 o;
        o.x = q.x + hp0 + b2[0];
        o.y = q.y + hp1 + b2[1];
        *(float2*)(out + ((size_t)b * T_LEN + (size_t)m * BATCH + lane) * 2) = o;
      }
      // (2) a1-proj, m = n-2, lane = t
      if (n >= 2 && n - 2 < NITV) {
        const int m = n - 2;
        float* pool = &P3[m % 3][0];
        float hr[64];
#pragma unroll
        for (int lq = 0; lq < 16; ++lq) {
          float4 v = *(const float4*)&pool[swz(lane, lq * 4)];
          hr[4*lq+0] = v.x; hr[4*lq+1] = v.y; hr[4*lq+2] = v.z; hr[4*lq+3] = v.w;
        }
        for (int g = 0; g < 8; ++g) {   // overwrite pool rows in place (own row only)
          const int jb = g * 8;
          float acc[8];
#pragma unroll
          for (int jj = 0; jj < 8; ++jj) acc[jj] = bih1[jb+jj] + bhh1[jb+jj];
#pragma unroll
          for (int jj = 0; jj < 8; ++jj) {
            const float* wr = Wih1 + (jb + jj) * 64;
#pragma unroll
            for (int k = 0; k < 64; ++k) acc[jj] = fmaf(wr[k], hr[k], acc[jj]);
          }
          *(float4*)&pool[swz(lane, jb)]     = make_float4(acc[0], acc[1], acc[2], acc[3]);
          *(float4*)&pool[swz(lane, jb + 4)] = make_float4(acc[4], acc[5], acc[6], acc[7]);
        }
      }
      // (3) head half j>=32, m = n-4 -> held partials
      if (n >= 4 && n - 4 < NITV) {
        const int m = n - 4;
        float hr[64];
#pragma unroll
        for (int lq = 0; lq < 16; ++lq) {
          float4 v = *(const float4*)&H1[m & 1][swz(lane, lq * 4)];
          hr[4*lq+0] = v.x; hr[4*lq+1] = v.y; hr[4*lq+2] = v.z; hr[4*lq+3] = v.w;
        }
        float p0 = 0.f, p1 = 0.f;
        for (int j = 32; j < 64; ++j) {
          float za = b1[j], zb = 0.f, zc = 0.f, zd = 0.f;
          const float* wr = W1 + j * 64;
#pragma unroll
          for (int k = 0; k < 64; k += 4) {
            za = fmaf(wr[k+0], hr[k+0], za); zb = fmaf(wr[k+1], hr[k+1], zb);
            zc = fmaf(wr[k+2], hr[k+2], zc); zd = fmaf(wr[k+3], hr[k+3], zd);
          }
          const float zv = fmaxf((za + zb) + (zc + zd), 0.f);
          p0 = fmaf(W2[j], zv, p0);
          p1 = fmaf(W2[64 + j], zv, p1);
        }
        hp0 = p0; hp1 = p1;
      }
      __syncthreads();
    }
  }
}

extern "C" void kernel_launch(void* const* d_in, const int* in_sizes, int n_in,
                              void* d_out, int out_size, void* d_ws, size_t ws_size,
                              hipStream_t stream) {
  (void)in_sizes; (void)n_in; (void)d_ws; (void)ws_size; (void)out_size;
  const float* x    = (const float*)d_in[0];
  const float* Wih0 = (const float*)d_in[1];
  const float* Whh0 = (const float*)d_in[2];
  const float* bih0 = (const float*)d_in[3];
  const float* bhh0 = (const float*)d_in[4];
  const float* Wih1 = (const float*)d_in[5];
  const float* Whh1 = (const float*)d_in[6];
  const float* bih1 = (const float*)d_in[7];
  const float* bhh1 = (const float*)d_in[8];
  const float* W1   = (const float*)d_in[9];
  const float* b1   = (const float*)d_in[10];
  const float* W2   = (const float*)d_in[11];
  const float* b2   = (const float*)d_in[12];
  float* out = (float*)d_out;

  rnn_fused<<<dim3(256), dim3(256), 0, stream>>>(
      x, Wih0, Whh0, bih0, bhh0, Wih1, Whh1, bih1, bhh1, W1, b1, W2, b2, out);
}

// Round 9
// 1564.732 us; speedup vs baseline: 1.0435x; 1.0435x over previous
//
#include <hip/hip_runtime.h>

// RNNPolicy fused kernel for MI355X — round 8 (fix swap32 result-register select).
// 256 blocks (1 chain/CU), 256 threads = 4 waves, interval = 64 timesteps.
// Recurrence: lane j computes outputs {j, j^32} over k-half (lane>>5): 8
// broadcast ds_read_b128 of h + 64 FMA + one permlane32_swap combine. h is
// carried wave-internally via a private LDS row (in-order b32 write -> reads).
//
// Pipeline (interval m at loop n):  P0(w0): a0-proj m=n, head-lo m=n-4, x-stage m=n+1
//   R0(w1): layer0 rec m=n-1        P1(w2): out m=n-5, a1-proj m=n-2 (in-place pool), head-hi m=n-4
//   R1(w3): layer1 rec m=n-3
// Tiles swizzled: logical col c of row t stored at c ^ ((t&15)<<2).

#define T_LEN 2048
#define BATCH 64
#define NITV  (T_LEN / BATCH)   // 32
#define NLOOP (NITV + 5)        // 37

__device__ __forceinline__ float tanh_fast(float x) {
  float e = __expf(2.0f * x);
  return fmaf(-2.0f, __builtin_amdgcn_rcpf(e + 1.0f), 1.0f);
}

__device__ __forceinline__ float swap32(float v) {
#if defined(__has_builtin) && __has_builtin(__builtin_amdgcn_permlane32_swap)
  // vdst'[i+32] = vsrc[i]; vsrc'[i] = vdst[i+32].  With both args = v:
  //   r[0][i+32] = v[i]  (partner for upper lanes)
  //   r[1][i]    = v[i+32] (partner for lower lanes)
  auto r = __builtin_amdgcn_permlane32_swap(__float_as_int(v), __float_as_int(v), false, false);
  return __int_as_float((threadIdx.x & 32) ? r[0] : r[1]);
#else
  return __shfl_xor(v, 32);
#endif
}

__global__ __launch_bounds__(256, 1) void rnn_fused(
    const float* __restrict__ x,
    const float* __restrict__ Wih0, const float* __restrict__ Whh0,
    const float* __restrict__ bih0, const float* __restrict__ bhh0,
    const float* __restrict__ Wih1, const float* __restrict__ Whh1,
    const float* __restrict__ bih1, const float* __restrict__ bhh1,
    const float* __restrict__ W1, const float* __restrict__ b1,
    const float* __restrict__ W2, const float* __restrict__ b2,
    float* __restrict__ out) {
  __shared__ __align__(16) float Xc [2][4096];   // x tiles (swizzled)
  __shared__ __align__(16) float A0t[2][4096];   // a0 tiles
  __shared__ __align__(16) float P3 [3][4096];   // h0 -> a1 in place, slot m%3
  __shared__ __align__(16) float H1t[2][4096];   // h1 tiles
  __shared__ __align__(16) float Hd0[2][64][2];  // head-lo partials
  __shared__ __align__(16) float Hrow0[64], Hrow1[64];  // private h rows (R waves)

  const int tid  = threadIdx.x;
  const int wave = tid >> 6;
  const int lane = tid & 63;
  const int b    = blockIdx.x;
  const size_t xbase = (size_t)b * T_LEN * 64;

  if (wave == 1) Hrow0[lane] = 0.f;   // h0[-1] = 0
  if (wave == 3) Hrow1[lane] = 0.f;   // h1[-1] = 0

  // Prologue: wave0 stages x interval 0 (swizzled).
  if (wave == 0) {
#pragma unroll
    for (int it = 0; it < 16; ++it) {
      const int fi = it * 64 + lane;              // float4 idx 0..1023
      const int t = fi >> 4, q = fi & 15;
      float4 v = *(const float4*)(x + xbase + fi * 4);
      *(float4*)&Xc[0][t * 64 + ((4 * q) ^ ((t & 15) << 2))] = v;
    }
  }
  __syncthreads();

  if (wave == 1 || wave == 3) {
    // ================= recurrence waves =================
    const float* Whh = (wave == 1) ? Whh0 : Whh1;
    const int half = lane >> 5;
    // wA: row `lane`, wB: row `lane^32`, both over k in [half*32, half*32+32)
    float wA[32], wB[32];
#pragma unroll
    for (int q = 0; q < 8; ++q) {
      float4 a4 = *(const float4*)(Whh + lane * 64 + half * 32 + 4 * q);
      float4 b4 = *(const float4*)(Whh + (lane ^ 32) * 64 + half * 32 + 4 * q);
      wA[4*q+0] = a4.x; wA[4*q+1] = a4.y; wA[4*q+2] = a4.z; wA[4*q+3] = a4.w;
      wB[4*q+0] = b4.x; wB[4*q+1] = b4.y; wB[4*q+2] = b4.z; wB[4*q+3] = b4.w;
    }
    float* Hrow = (wave == 1) ? Hrow0 : Hrow1;
    const float* hb = Hrow + half * 32;
    const int dly = (wave == 1) ? 1 : 3;

    for (int n = 0; n < NLOOP; ++n) {
      const int m = n - dly;
      if (m >= 0 && m < NITV) {
        const float* Ain = (wave == 1) ? &A0t[m & 1][0] : &P3[m % 3][0];
        float* Hout      = (wave == 1) ? &P3[m % 3][0] : &H1t[m & 1][0];
#pragma unroll 8
        for (int tt = 0; tt < BATCH; ++tt) {
          const int xr  = (tt & 15) << 2;
          const int idx = tt * 64 + (lane ^ xr);
          const float av = Ain[idx];
          // broadcast h half (written by this wave last step; DS in-order)
          float4 h0 = *(const float4*)(hb + 0);
          float4 h1 = *(const float4*)(hb + 4);
          float4 h2 = *(const float4*)(hb + 8);
          float4 h3 = *(const float4*)(hb + 12);
          float4 h4 = *(const float4*)(hb + 16);
          float4 h5 = *(const float4*)(hb + 20);
          float4 h6 = *(const float4*)(hb + 24);
          float4 h7 = *(const float4*)(hb + 28);
          float a0 = 0.f, a1 = 0.f, a2 = 0.f, a3 = 0.f;
          float c0 = 0.f, c1 = 0.f, c2 = 0.f, c3 = 0.f;
#define FQ(hv, qq) \
          a0 = fmaf(hv.x, wA[4*qq+0], a0); c0 = fmaf(hv.x, wB[4*qq+0], c0); \
          a1 = fmaf(hv.y, wA[4*qq+1], a1); c1 = fmaf(hv.y, wB[4*qq+1], c1); \
          a2 = fmaf(hv.z, wA[4*qq+2], a2); c2 = fmaf(hv.z, wB[4*qq+2], c2); \
          a3 = fmaf(hv.w, wA[4*qq+3], a3); c3 = fmaf(hv.w, wB[4*qq+3], c3);
          FQ(h0, 0) FQ(h1, 1) FQ(h2, 2) FQ(h3, 3)
          FQ(h4, 4) FQ(h5, 5) FQ(h6, 6) FQ(h7, 7)
#undef FQ
          const float selfp  = (a0 + a1) + (a2 + a3);
          const float otherp = (c0 + c1) + (c2 + c3);
          const float pre = av + selfp + swap32(otherp);
          const float h = tanh_fast(pre);
          Hrow[lane] = h;        // next step's broadcast source
          Hout[idx]  = h;        // consumer tile (swizzled)
        }
      }
      __syncthreads();
    }
  } else if (wave == 0) {
    // ================= P0: x-stage + a0-proj + head-lo =================
    const int sw = (lane & 15) << 2;
    for (int n = 0; n < NLOOP; ++n) {
      // (1) issue global loads for x interval n+1
      float4 px[16];
      const bool st = (n + 1) < NITV;
      if (st) {
        const float* src = x + xbase + (size_t)(n + 1) * BATCH * 64;
#pragma unroll
        for (int it = 0; it < 16; ++it) px[it] = *(const float4*)(src + (it * 64 + lane) * 4);
      }
      // (2) a0-proj, m=n, lane = t
      if (n < NITV) {
        float xr[64];
#pragma unroll
        for (int q = 0; q < 16; ++q)
          *(float4*)&xr[4 * q] = *(const float4*)&Xc[n & 1][lane * 64 + ((4 * q) ^ sw)];
        float* Aout = &A0t[n & 1][0];
        for (int g = 0; g < 8; ++g) {
          const int jb = g * 8;
          float acc[8];
#pragma unroll
          for (int jj = 0; jj < 8; ++jj) acc[jj] = bih0[jb + jj] + bhh0[jb + jj];
#pragma unroll
          for (int jj = 0; jj < 8; ++jj) {
            const float* wr = Wih0 + (jb + jj) * 64;
#pragma unroll
            for (int k = 0; k < 64; ++k) acc[jj] = fmaf(wr[k], xr[k], acc[jj]);
          }
          *(float4*)&Aout[lane * 64 + (jb ^ sw)]       = make_float4(acc[0], acc[1], acc[2], acc[3]);
          *(float4*)&Aout[lane * 64 + ((jb + 4) ^ sw)] = make_float4(acc[4], acc[5], acc[6], acc[7]);
        }
      }
      // (3) head-lo j<32, m = n-4
      if (n >= 4 && n - 4 < NITV) {
        const int m = n - 4;
        float hr[64];
#pragma unroll
        for (int q = 0; q < 16; ++q)
          *(float4*)&hr[4 * q] = *(const float4*)&H1t[m & 1][lane * 64 + ((4 * q) ^ sw)];
        float p0 = 0.f, p1 = 0.f;
        for (int j = 0; j < 32; ++j) {
          float za = b1[j], zb = 0.f, zc = 0.f, zd = 0.f;
          const float* wr = W1 + j * 64;
#pragma unroll
          for (int k = 0; k < 64; k += 4) {
            za = fmaf(wr[k+0], hr[k+0], za); zb = fmaf(wr[k+1], hr[k+1], zb);
            zc = fmaf(wr[k+2], hr[k+2], zc); zd = fmaf(wr[k+3], hr[k+3], zd);
          }
          const float zv = fmaxf((za + zb) + (zc + zd), 0.f);
          p0 = fmaf(W2[j], zv, p0);
          p1 = fmaf(W2[64 + j], zv, p1);
        }
        *(float2*)&Hd0[m & 1][lane][0] = make_float2(p0, p1);
      }
      // (4) write staged x (swizzled)
      if (st) {
#pragma unroll
        for (int it = 0; it < 16; ++it) {
          const int fi = it * 64 + lane;
          const int t = fi >> 4, q = fi & 15;
          *(float4*)&Xc[(n + 1) & 1][t * 64 + ((4 * q) ^ ((t & 15) << 2))] = px[it];
        }
      }
      __syncthreads();
    }
  } else {
    // ================= P1: out-store + a1-proj + head-hi =================
    const int sw = (lane & 15) << 2;
    float hp0 = 0.f, hp1 = 0.f;
    for (int n = 0; n < NLOOP; ++n) {
      // (1) combine + store out, m = n-5 (hp* computed last iter for same m)
      if (n >= 5 && n - 5 < NITV) {
        const int m = n - 5;
        const float2 q2 = *(const float2*)&Hd0[m & 1][lane][0];
        float2 o;
        o.x = q2.x + hp0 + b2[0];
        o.y = q2.y + hp1 + b2[1];
        *(float2*)(out + ((size_t)b * T_LEN + (size_t)m * BATCH + lane) * 2) = o;
      }
      // (2) a1-proj, m = n-2, lane = t (in-place pool overwrite, own row only)
      if (n >= 2 && n - 2 < NITV) {
        const int m = n - 2;
        float* pool = &P3[m % 3][0];
        float hr[64];
#pragma unroll
        for (int q = 0; q < 16; ++q)
          *(float4*)&hr[4 * q] = *(const float4*)&pool[lane * 64 + ((4 * q) ^ sw)];
        for (int g = 0; g < 8; ++g) {
          const int jb = g * 8;
          float acc[8];
#pragma unroll
          for (int jj = 0; jj < 8; ++jj) acc[jj] = bih1[jb + jj] + bhh1[jb + jj];
#pragma unroll
          for (int jj = 0; jj < 8; ++jj) {
            const float* wr = Wih1 + (jb + jj) * 64;
#pragma unroll
            for (int k = 0; k < 64; ++k) acc[jj] = fmaf(wr[k], hr[k], acc[jj]);
          }
          *(float4*)&pool[lane * 64 + (jb ^ sw)]       = make_float4(acc[0], acc[1], acc[2], acc[3]);
          *(float4*)&pool[lane * 64 + ((jb + 4) ^ sw)] = make_float4(acc[4], acc[5], acc[6], acc[7]);
        }
      }
      // (3) head-hi j>=32, m = n-4 -> held partials
      if (n >= 4 && n - 4 < NITV) {
        const int m = n - 4;
        float hr[64];
#pragma unroll
        for (int q = 0; q < 16; ++q)
          *(float4*)&hr[4 * q] = *(const float4*)&H1t[m & 1][lane * 64 + ((4 * q) ^ sw)];
        float p0 = 0.f, p1 = 0.f;
        for (int j = 32; j < 64; ++j) {
          float za = b1[j], zb = 0.f, zc = 0.f, zd = 0.f;
          const float* wr = W1 + j * 64;
#pragma unroll
          for (int k = 0; k < 64; k += 4) {
            za = fmaf(wr[k+0], hr[k+0], za); zb = fmaf(wr[k+1], hr[k+1], zb);
            zc = fmaf(wr[k+2], hr[k+2], zc); zd = fmaf(wr[k+3], hr[k+3], zd);
          }
          const float zv = fmaxf((za + zb) + (zc + zd), 0.f);
          p0 = fmaf(W2[j], zv, p0);
          p1 = fmaf(W2[64 + j], zv, p1);
        }
        hp0 = p0; hp1 = p1;
      }
      __syncthreads();
    }
  }
}

extern "C" void kernel_launch(void* const* d_in, const int* in_sizes, int n_in,
                              void* d_out, int out_size, void* d_ws, size_t ws_size,
                              hipStream_t stream) {
  (void)in_sizes; (void)n_in; (void)d_ws; (void)ws_size; (void)out_size;
  const float* x    = (const float*)d_in[0];
  const float* Wih0 = (const float*)d_in[1];
  const float* Whh0 = (const float*)d_in[2];
  const float* bih0 = (const float*)d_in[3];
  const float* bhh0 = (const float*)d_in[4];
  const float* Wih1 = (const float*)d_in[5];
  const float* Whh1 = (const float*)d_in[6];
  const float* bih1 = (const float*)d_in[7];
  const float* bhh1 = (const float*)d_in[8];
  const float* W1   = (const float*)d_in[9];
  const float* b1   = (const float*)d_in[10];
  const float* W2   = (const float*)d_in[11];
  const float* b2   = (const float*)d_in[12];
  float* out = (float*)d_out;

  rnn_fused<<<dim3(256), dim3(256), 0, stream>>>(
      x, Wih0, Whh0, bih0, bhh0, Wih1, Whh1, bih1, bhh1, W1, b1, W2, b2, out);
}